// Round 4
// baseline (181.064 us; speedup 1.0000x reference)
//
#include <hip/hip_runtime.h>

#define DIM   1024
#define NQKV  3072
#define SEQ   2048
#define HEADS 16
#define DHEAD 64
#define M_TOT 4096   // batch(2) * seq(2048)

typedef __bf16 bf16;
typedef __bf16 bf16x8 __attribute__((ext_vector_type(8)));
typedef float  f32x4  __attribute__((ext_vector_type(4)));

typedef const __attribute__((address_space(1))) unsigned int gu32;
typedef __attribute__((address_space(3))) unsigned int su32;

static __device__ __forceinline__ unsigned short f2b(float f) {
    bf16 h = (bf16)f;
    return __builtin_bit_cast(unsigned short, h);
}

// ---------------- kernel 1: fused prep (cast x -> bf16 | transpose+scale W) ----------------
// R8: transpose in 64x64 tiles, float4 global reads, uint4 global writes.
#define CAST_BLOCKS (M_TOT * DIM / (256 * 4))
#define TR_NB (NQKV / 64)   // 48
__global__ void prep_kernel(const float* __restrict__ x,
                            unsigned short* __restrict__ xb,
                            const float* __restrict__ W,
                            unsigned short* __restrict__ Wt) {
    __shared__ float tile[64][65];   // [n_local][k_local], padded
    const int id  = blockIdx.x;
    const int tid = threadIdx.x;
    if (id < CAST_BLOCKS) {
        int i = (id * 256 + tid) * 4;
        float4 v = *(const float4*)(x + i);
        ushort4 o;
        o.x = f2b(v.x); o.y = f2b(v.y); o.z = f2b(v.z); o.w = f2b(v.w);
        *(ushort4*)(xb + i) = o;
    } else {
        int t  = id - CAST_BLOCKS;
        int nb = t % TR_NB;
        int kb = t / TR_NB;          // 0..15
        #pragma unroll
        for (int p = 0; p < 4; p++) {
            int kl = p * 16 + (tid >> 4);        // 0..63
            int nl = (tid & 15) * 4;             // 0..60
            float4 v = *(const float4*)&W[(size_t)(kb * 64 + kl) * NQKV + nb * 64 + nl];
            tile[nl + 0][kl] = v.x;
            tile[nl + 1][kl] = v.y;
            tile[nl + 2][kl] = v.z;
            tile[nl + 3][kl] = v.w;
        }
        __syncthreads();
        #pragma unroll
        for (int p = 0; p < 2; p++) {
            int nl = p * 32 + (tid >> 3);        // 0..63
            int k8 = (tid & 7) * 8;              // 0..56
            int n  = nb * 64 + nl;
            float s = (n < 1024) ? 0.18033688f : 1.0f;   // 0.125 * log2(e)
            float4 a = *(const float4*)&tile[nl][k8];
            float4 b = *(const float4*)&tile[nl][k8 + 4];
            ushort4 o0, o1;
            o0.x = f2b(a.x * s); o0.y = f2b(a.y * s); o0.z = f2b(a.z * s); o0.w = f2b(a.w * s);
            o1.x = f2b(b.x * s); o1.y = f2b(b.y * s); o1.z = f2b(b.z * s); o1.w = f2b(b.w * s);
            uint4 pk;
            pk.x = ((unsigned)o0.y << 16) | o0.x;
            pk.y = ((unsigned)o0.w << 16) | o0.z;
            pk.z = ((unsigned)o1.y << 16) | o1.x;
            pk.w = ((unsigned)o1.w << 16) | o1.z;
            *(uint4*)&Wt[(size_t)n * DIM + kb * 64 + k8] = pk;
        }
    }
}

// ---------------- kernel 2: QKV GEMM, LDS-restaged coalesced epilogue ----------------
#define LDC 136
__global__ __launch_bounds__(256) void qkv_gemm_kernel(
    const unsigned short* __restrict__ A,
    const unsigned short* __restrict__ Bt,
    unsigned short* __restrict__ Qw,
    unsigned short* __restrict__ Kw,
    unsigned short* __restrict__ Vtw)
{
    __shared__ __align__(16) unsigned char smem[128 * LDC * 2];   // 34816 B
    unsigned short* As = (unsigned short*)smem;
    unsigned short* Bs = (unsigned short*)(smem + 16384);
    unsigned short* Cs = (unsigned short*)smem;

    const int tid  = threadIdx.x;
    const int m0   = blockIdx.y * 128;
    const int n0   = blockIdx.x * 128;
    const int w    = tid >> 6;
    const int lane = tid & 63;
    const int l16  = lane & 15;
    const int quad = lane >> 4;
    const int wm   = (w >> 1) * 64;
    const int wn   = (w & 1) * 64;
    const int srow = lane >> 3;
    const int scol = (lane & 7) * 8;

    f32x4 acc[4][4];
    const f32x4 fzero = {0.f, 0.f, 0.f, 0.f};
    for (int i = 0; i < 4; i++)
        for (int j = 0; j < 4; j++) acc[i][j] = fzero;

    const unsigned short* Ag = A  + (size_t)(m0 + w * 32 + srow) * DIM + scol;
    const unsigned short* Bg = Bt + (size_t)(n0 + w * 32 + srow) * DIM + scol;

    for (int kt = 0; kt < DIM; kt += 64) {
        #pragma unroll
        for (int j = 0; j < 4; j++) {
            __builtin_amdgcn_global_load_lds((gu32*)(Ag + kt + (size_t)j * 8 * DIM),
                                             (su32*)&As[(w * 32 + j * 8) * 64], 16, 0, 0);
            __builtin_amdgcn_global_load_lds((gu32*)(Bg + kt + (size_t)j * 8 * DIM),
                                             (su32*)&Bs[(w * 32 + j * 8) * 64], 16, 0, 0);
        }
        __syncthreads();
        #pragma unroll
        for (int s = 0; s < 2; s++) {
            bf16x8 af[4], bfr[4];
            #pragma unroll
            for (int i = 0; i < 4; i++) {
                af[i]  = *(const bf16x8*)(&As[(wm + i * 16 + l16) * 64 + s * 32 + quad * 8]);
                bfr[i] = *(const bf16x8*)(&Bs[(wn + i * 16 + l16) * 64 + s * 32 + quad * 8]);
            }
            #pragma unroll
            for (int i = 0; i < 4; i++)
                #pragma unroll
                for (int j = 0; j < 4; j++)
                    acc[i][j] = __builtin_amdgcn_mfma_f32_16x16x32_bf16(af[i], bfr[j], acc[i][j], 0, 0, 0);
        }
        __syncthreads();
    }

    const int part = n0 >> 10;
    const int h0   = (n0 & 1023) >> 6;
    const int b    = m0 >> 11;
    const int np0  = m0 & 2047;

    if (part < 2) {
        #pragma unroll
        for (int i = 0; i < 4; i++)
            #pragma unroll
            for (int j = 0; j < 4; j++)
                #pragma unroll
                for (int r = 0; r < 4; r++)
                    Cs[(wm + i * 16 + quad * 4 + r) * LDC + wn + j * 16 + l16] = f2b(acc[i][j][r]);
        __syncthreads();
        unsigned short* dst = (part == 0) ? Qw : Kw;
        #pragma unroll
        for (int pass = 0; pass < 8; pass++) {
            int mi = pass * 16 + (tid >> 4);
            int ci = (tid & 15) * 8;
            uint4 v = *(const uint4*)&Cs[mi * LDC + ci];
            int bh = b * HEADS + h0 + (ci >> 6);
            *(uint4*)&dst[((size_t)bh * SEQ + np0 + mi) * DHEAD + (ci & 63)] = v;
        }
    } else {
        #pragma unroll
        for (int i = 0; i < 4; i++)
            #pragma unroll
            for (int j = 0; j < 4; j++) {
                ushort4 pk;
                pk.x = f2b(acc[i][j][0]); pk.y = f2b(acc[i][j][1]);
                pk.z = f2b(acc[i][j][2]); pk.w = f2b(acc[i][j][3]);
                *(ushort4*)&Cs[(wn + j * 16 + l16) * LDC + wm + i * 16 + quad * 4] = pk;
            }
        __syncthreads();
        #pragma unroll
        for (int pass = 0; pass < 8; pass++) {
            int ci = pass * 16 + (tid >> 4);
            int mi = (tid & 15) * 8;
            uint4 v = *(const uint4*)&Cs[ci * LDC + mi];
            int bh = b * HEADS + h0 + (ci >> 6);
            *(uint4*)&Vtw[((size_t)bh * DHEAD + (ci & 63)) * SEQ + np0 + mi] = v;
        }
    }
}

// ---------------- kernel 3: flash attention + residual ----------------
// R10: R3 counters (occupancy 18.8%, no pipe >45%, conflict counter proven
// structural at 4/b128) => latency-bound at 2 waves/SIMD. Restructure: the 4
// waves of a block = 2 q-groups x 2 key-halves. Each wave: 64 queries (4
// independent qh dep-chains) x 1024 keys (16 tiles). Each kf/vf LDS read
// feeds 4 MFMAs (LDS traffic halves again); 4 chains fill dependency stalls;
// barriers halve. Key-half partials (o, dsum) summed through LDS scratch in
// the epilogue; division after the sum. Grid/occupancy unchanged (512 blocks,
// 2/CU); LDS 73.7KB/block.
#define LDK 72
#define TILE_E (64 * LDK)       // ushorts per staged tile
#define KT 16                   // key tiles per key-half
__global__ __launch_bounds__(256) void attn_kernel(
    const unsigned short* __restrict__ Qw,
    const unsigned short* __restrict__ Kw,
    const unsigned short* __restrict__ Vtw,
    const float* __restrict__ x,
    float* __restrict__ out)
{
    __shared__ __align__(16) unsigned char smem[TILE_E * 8 * 2];   // 73728 B
    unsigned short* Ks = (unsigned short*)smem;                    // [buf][pair][64][LDK]
    unsigned short* Vs = (unsigned short*)(smem + TILE_E * 4 * 2); // [buf][pair] V^T [d][key]
    float* scratch = (float*)smem;                                 // epilogue reuse (43008 B)

    const int id  = blockIdx.x;
    const int qt  = id >> 5;                                // 0..15 (128-query tiles)
    const int bh  = ((id & 7) << 2) | ((id >> 3) & 3);      // 4 bh per XCD
    const int tid = threadIdx.x;
    const int w   = tid >> 6, lane = tid & 63;
    const int l16 = lane & 15, quad = lane >> 4;
    const int g   = w & 1;      // q-group (64 queries)
    const int p   = w >> 1;     // key-half (1024 keys)

    const unsigned short* Qb = Qw + ((size_t)bh * SEQ + qt * 128 + g * 64 + l16) * DHEAD;
    bf16x8 qf[4][2];
    #pragma unroll
    for (int qh = 0; qh < 4; qh++) {
        qf[qh][0] = *(const bf16x8*)(Qb + qh * 16 * DHEAD + quad * 8);
        qf[qh][1] = *(const bf16x8*)(Qb + qh * 16 * DHEAD + 32 + quad * 8);
    }

    bf16x8 ones;
    #pragma unroll
    for (int j = 0; j < 8; j++) ones[j] = (bf16)1.0f;

    f32x4 o[4][4], dsum[4];
    const f32x4 fzero = {0.f, 0.f, 0.f, 0.f};
    #pragma unroll
    for (int qh = 0; qh < 4; qh++) {
        #pragma unroll
        for (int d = 0; d < 4; d++) o[qh][d] = fzero;
        dsum[qh] = fzero;
    }

    const unsigned short* Kg = Kw  + (size_t)bh * SEQ * DHEAD;
    const unsigned short* Vg = Vtw + (size_t)bh * DHEAD * SEQ;

    const int r0 = tid >> 3, c0 = (tid & 7) * 8;
    // physical Ks row for logical key r0: p = ki*16 + l16 (read-permutation inverse)
    const int pr0 = ((r0 >> 2) & 1) * 16 + ((r0 >> 3) & 3) * 4 + (r0 & 3);

    // prologue: tile 0 of both key-halves -> buf 0
    uint4 k00 = *(const uint4*)(Kg + (size_t)r0 * DHEAD + c0);
    uint4 k01 = *(const uint4*)(Kg + (size_t)(r0 + 32) * DHEAD + c0);
    uint4 k10 = *(const uint4*)(Kg + (size_t)(1024 + r0) * DHEAD + c0);
    uint4 k11 = *(const uint4*)(Kg + (size_t)(1024 + r0 + 32) * DHEAD + c0);
    uint4 v00 = *(const uint4*)(Vg + (size_t)r0 * SEQ + c0);
    uint4 v01 = *(const uint4*)(Vg + (size_t)(r0 + 32) * SEQ + c0);
    uint4 v10 = *(const uint4*)(Vg + (size_t)r0 * SEQ + 1024 + c0);
    uint4 v11 = *(const uint4*)(Vg + (size_t)(r0 + 32) * SEQ + 1024 + c0);
    *(uint4*)&Ks[0 * TILE_E + pr0 * LDK + c0]        = k00;
    *(uint4*)&Ks[0 * TILE_E + (pr0 + 32) * LDK + c0] = k01;
    *(uint4*)&Ks[1 * TILE_E + pr0 * LDK + c0]        = k10;
    *(uint4*)&Ks[1 * TILE_E + (pr0 + 32) * LDK + c0] = k11;
    *(uint4*)&Vs[0 * TILE_E + r0 * LDK + c0]         = v00;
    *(uint4*)&Vs[0 * TILE_E + (r0 + 32) * LDK + c0]  = v01;
    *(uint4*)&Vs[1 * TILE_E + r0 * LDK + c0]         = v10;
    *(uint4*)&Vs[1 * TILE_E + (r0 + 32) * LDK + c0]  = v11;
    // prefetch tile 1 of both halves into regs
    k00 = *(const uint4*)(Kg + (size_t)(64 + r0) * DHEAD + c0);
    k01 = *(const uint4*)(Kg + (size_t)(64 + r0 + 32) * DHEAD + c0);
    k10 = *(const uint4*)(Kg + (size_t)(1024 + 64 + r0) * DHEAD + c0);
    k11 = *(const uint4*)(Kg + (size_t)(1024 + 64 + r0 + 32) * DHEAD + c0);
    v00 = *(const uint4*)(Vg + (size_t)r0 * SEQ + 64 + c0);
    v01 = *(const uint4*)(Vg + (size_t)(r0 + 32) * SEQ + 64 + c0);
    v10 = *(const uint4*)(Vg + (size_t)r0 * SEQ + 1024 + 64 + c0);
    v11 = *(const uint4*)(Vg + (size_t)(r0 + 32) * SEQ + 1024 + 64 + c0);

    for (int t = 0; t < KT; t++) {
        const int cur = t & 1, nxt = cur ^ 1;
        __syncthreads();
        // stage tile t+1 (both halves) into the buffer nobody reads this iter
        *(uint4*)&Ks[(nxt * 2 + 0) * TILE_E + pr0 * LDK + c0]        = k00;
        *(uint4*)&Ks[(nxt * 2 + 0) * TILE_E + (pr0 + 32) * LDK + c0] = k01;
        *(uint4*)&Ks[(nxt * 2 + 1) * TILE_E + pr0 * LDK + c0]        = k10;
        *(uint4*)&Ks[(nxt * 2 + 1) * TILE_E + (pr0 + 32) * LDK + c0] = k11;
        *(uint4*)&Vs[(nxt * 2 + 0) * TILE_E + r0 * LDK + c0]         = v00;
        *(uint4*)&Vs[(nxt * 2 + 0) * TILE_E + (r0 + 32) * LDK + c0]  = v01;
        *(uint4*)&Vs[(nxt * 2 + 1) * TILE_E + r0 * LDK + c0]         = v10;
        *(uint4*)&Vs[(nxt * 2 + 1) * TILE_E + (r0 + 32) * LDK + c0]  = v11;
        // issue global loads of tile t+2 (both halves)
        int kvn = ((t + 2) & (KT - 1)) * 64;
        k00 = *(const uint4*)(Kg + (size_t)(kvn + r0) * DHEAD + c0);
        k01 = *(const uint4*)(Kg + (size_t)(kvn + r0 + 32) * DHEAD + c0);
        k10 = *(const uint4*)(Kg + (size_t)(1024 + kvn + r0) * DHEAD + c0);
        k11 = *(const uint4*)(Kg + (size_t)(1024 + kvn + r0 + 32) * DHEAD + c0);
        v00 = *(const uint4*)(Vg + (size_t)r0 * SEQ + kvn + c0);
        v01 = *(const uint4*)(Vg + (size_t)(r0 + 32) * SEQ + kvn + c0);
        v10 = *(const uint4*)(Vg + (size_t)r0 * SEQ + 1024 + kvn + c0);
        v11 = *(const uint4*)(Vg + (size_t)(r0 + 32) * SEQ + 1024 + kvn + c0);

        // S^T = K_perm · Q^T for 4 query-sixteens; each kf read feeds 4 MFMAs
        const unsigned short* Kb = Ks + (size_t)(cur * 2 + p) * TILE_E;
        f32x4 sacc[4][4];   // [qh][ki]
        #pragma unroll
        for (int qh = 0; qh < 4; qh++)
            #pragma unroll
            for (int ki = 0; ki < 4; ki++) sacc[qh][ki] = fzero;
        #pragma unroll
        for (int s = 0; s < 2; s++)
            #pragma unroll
            for (int ki = 0; ki < 4; ki++) {
                bf16x8 kf = *(const bf16x8*)(&Kb[(ki * 16 + l16) * LDK + s * 32 + quad * 8]);
                #pragma unroll
                for (int qh = 0; qh < 4; qh++)
                    sacc[qh][ki] = __builtin_amdgcn_mfma_f32_16x16x32_bf16(kf, qf[qh][s], sacc[qh][ki], 0, 0, 0);
            }

        // p = exp2(s); C-regs are the PV A-frags; denominator via ones-MFMA
        bf16x8 pf[4][2];
        #pragma unroll
        for (int qh = 0; qh < 4; qh++)
            #pragma unroll
            for (int s = 0; s < 2; s++)
                #pragma unroll
                for (int half = 0; half < 2; half++) {
                    int ki = 2 * s + half;
                    #pragma unroll
                    for (int r = 0; r < 4; r++)
                        pf[qh][s][half * 4 + r] = (bf16)__builtin_amdgcn_exp2f(sacc[qh][ki][r]);
                }

        const unsigned short* Vb = Vs + (size_t)(cur * 2 + p) * TILE_E;
        #pragma unroll
        for (int s = 0; s < 2; s++) {
            #pragma unroll
            for (int qh = 0; qh < 4; qh++)
                dsum[qh] = __builtin_amdgcn_mfma_f32_16x16x32_bf16(pf[qh][s], ones, dsum[qh], 0, 0, 0);
            #pragma unroll
            for (int d = 0; d < 4; d++) {
                bf16x8 vf = *(const bf16x8*)(&Vb[(d * 16 + l16) * LDK + s * 32 + quad * 8]);
                #pragma unroll
                for (int qh = 0; qh < 4; qh++)
                    o[qh][d] = __builtin_amdgcn_mfma_f32_16x16x32_bf16(pf[qh][s], vf, o[qh][d], 0, 0, 0);
            }
        }
    }

    // ---- combine the two key-half partials through LDS scratch ----
    __syncthreads();   // all waves done reading K/V LDS
    if (w >= 2) {      // key-half 1 writes its partials
        float* sc = scratch + ((size_t)((w - 2) * 64 + lane)) * 84;   // 84f stride: 16B-aligned, padded
        #pragma unroll
        for (int qh = 0; qh < 4; qh++) {
            #pragma unroll
            for (int di = 0; di < 4; di++)
                *(f32x4*)(sc + (qh * 4 + di) * 4) = o[qh][di];
            *(f32x4*)(sc + 64 + qh * 4) = dsum[qh];
        }
    }
    __syncthreads();
    if (w < 2) {
        float* sc = scratch + ((size_t)(w * 64 + lane)) * 84;
        #pragma unroll
        for (int qh = 0; qh < 4; qh++) {
            #pragma unroll
            for (int di = 0; di < 4; di++)
                o[qh][di] += *(const f32x4*)(sc + (qh * 4 + di) * 4);
            dsum[qh] += *(const f32x4*)(sc + 64 + qh * 4);
        }
        const int b = bh >> 4, h = bh & 15;
        #pragma unroll
        for (int qh = 0; qh < 4; qh++) {
            float lr[4];
            #pragma unroll
            for (int r = 0; r < 4; r++) lr[r] = __builtin_amdgcn_rcpf(dsum[qh][r]);
            #pragma unroll
            for (int di = 0; di < 4; di++)
                #pragma unroll
                for (int r = 0; r < 4; r++) {
                    int np  = qt * 128 + g * 64 + qh * 16 + quad * 4 + r;
                    int col = h * 64 + di * 16 + l16;
                    size_t gidx = ((size_t)(b * SEQ + np)) * DIM + col;
                    out[gidx] = o[qh][di][r] * lr[r] + x[gidx];
                }
        }
    }
}

extern "C" void kernel_launch(void* const* d_in, const int* in_sizes, int n_in,
                              void* d_out, int out_size, void* d_ws, size_t ws_size,
                              hipStream_t stream) {
    const float* x  = (const float*)d_in[0];   // [2,2048,1024]
    const float* Wq = (const float*)d_in[1];   // [1024,3072]
    float* out = (float*)d_out;

    unsigned short* xb = (unsigned short*)d_ws;                  // [4096][1024]
    unsigned short* Wt = xb + (size_t)M_TOT * DIM;               // [3072][1024]
    unsigned short* Qw = Wt + (size_t)NQKV * DIM;                // [32][2048][64]
    unsigned short* Kw = Qw + (size_t)32 * SEQ * DHEAD;          // [32][2048][64]
    unsigned short* Vt = Kw + (size_t)32 * SEQ * DHEAD;          // [32][64][2048]

    prep_kernel<<<CAST_BLOCKS + TR_NB * (DIM / 64), 256, 0, stream>>>(x, xb, Wq, Wt);
    qkv_gemm_kernel<<<dim3(NQKV / 128, M_TOT / 128), 256, 0, stream>>>(xb, Wt, Qw, Kw, Vt);
    attn_kernel<<<(SEQ / 128) * 32, 256, 0, stream>>>(Qw, Kw, Vt, x, out);
}